// Round 1
// baseline (200.586 us; speedup 1.0000x reference)
//
#include <hip/hip_runtime.h>
#include <cfloat>

#define NSEG 512
#define C 21

// ---- NN kernel config ----
#define K1_THREADS 512
#define QT 4                      // queries per thread
#define QPB (K1_THREADS * QT)     // 2048 queries per block
#define PPB 1024                  // points per block tile

// K1: for each query chunk x point chunk, compute partial argmin of
// val = |p|^2 - 2 q.p   (the |q|^2 term is constant per query -> argmin-invariant)
// in f64 so that argmin matches a high-precision reference.
__global__ __launch_bounds__(K1_THREADS)
void nn_partial(const float* __restrict__ pts, const float* __restrict__ dpts,
                int n, int m, double* __restrict__ pdist, int* __restrict__ pidx) {
    __shared__ float4 lp[PPB];
    __shared__ double lpsum[PPB];
    const int qc = blockIdx.x, pc = blockIdx.y;
    const int t = threadIdx.x;
    const int pbase = pc * PPB;

    for (int j = t; j < PPB; j += K1_THREADS) {
        int p = pbase + j;
        float x = 0.f, y = 0.f, z = 0.f;
        double ps = 1e300;
        if (p < n) {
            x = pts[(size_t)p * 3 + 0];
            y = pts[(size_t)p * 3 + 1];
            z = pts[(size_t)p * 3 + 2];
            double dx = (double)x, dy = (double)y, dz = (double)z;
            ps = dx * dx + dy * dy + dz * dz;
        }
        lp[j] = make_float4(x, y, z, 0.f);
        lpsum[j] = ps;
    }
    __syncthreads();

    double m2x[QT], m2y[QT], m2z[QT], best[QT];
    int bidx[QT], qv[QT];
#pragma unroll
    for (int k = 0; k < QT; k++) {
        int qi = qc * QPB + t + k * K1_THREADS;
        qv[k] = qi;
        double dx = 0.0, dy = 0.0, dz = 0.0;
        if (qi < m) {
            dx = (double)dpts[(size_t)qi * 3 + 0];
            dy = (double)dpts[(size_t)qi * 3 + 1];
            dz = (double)dpts[(size_t)qi * 3 + 2];
        }
        m2x[k] = -2.0 * dx; m2y[k] = -2.0 * dy; m2z[k] = -2.0 * dz;
        best[k] = 1e308; bidx[k] = 0;
    }

    const int pcount = min(PPB, n - pbase);
#pragma unroll 2
    for (int j = 0; j < pcount; j++) {
        float4 p = lp[j];
        double psum = lpsum[j];
        double px = (double)p.x, py = (double)p.y, pz = (double)p.z;
#pragma unroll
        for (int k = 0; k < QT; k++) {
            double v = fma(px, m2x[k], fma(py, m2y[k], fma(pz, m2z[k], psum)));
            if (v < best[k]) { best[k] = v; bidx[k] = pbase + j; }  // strict < : first (lowest idx) min wins
        }
    }

#pragma unroll
    for (int k = 0; k < QT; k++) {
        int qi = qv[k];
        if (qi < m) {
            pdist[(size_t)pc * m + qi] = best[k];   // [pc][qi] layout -> coalesced both sides
            pidx[(size_t)pc * m + qi] = bidx[k];
        }
    }
}

// K2: reduce partials over point-chunks (ascending chunk order, strict < keeps lowest index)
__global__ __launch_bounds__(256)
void nn_reduce(const double* __restrict__ pdist, const int* __restrict__ pidx,
               int* __restrict__ nn_idx, int m, int PC) {
    int i = blockIdx.x * 256 + threadIdx.x;
    if (i >= m) return;
    double b = 1e308; int bi = 0;
    for (int p = 0; p < PC; p++) {
        double d = pdist[(size_t)p * m + i];
        int ix = pidx[(size_t)p * m + i];
        if (d < b) { b = d; bi = ix; }
    }
    nn_idx[i] = bi;
}

// K3: per-256-element-chunk histogram of sptids (integer LDS atomics -> deterministic)
__global__ __launch_bounds__(256)
void chunk_hist(const int* __restrict__ sptids, int* __restrict__ chunkhist, int m) {
    __shared__ int h[NSEG];
    int ch = blockIdx.x, t = threadIdx.x;
    h[t] = 0; h[t + 256] = 0;
    __syncthreads();
    int i = ch * 256 + t;
    if (i < m) atomicAdd(&h[sptids[i]], 1);
    __syncthreads();
    chunkhist[ch * NSEG + t] = h[t];
    chunkhist[ch * NSEG + t + 256] = h[t + 256];
}

// K4: one block, 512 threads. totals -> exclusive scan over segments -> per-chunk offsets
__global__ __launch_bounds__(NSEG)
void seg_offsets(const int* __restrict__ chunkhist, int* __restrict__ chunkoff, int nch) {
    __shared__ int tot[NSEG];
    int s = threadIdx.x;
    int sum = 0;
    for (int c = 0; c < nch; c++) sum += chunkhist[c * NSEG + s];
    tot[s] = sum;
    __syncthreads();
    int incl = sum;
    for (int off = 1; off < NSEG; off <<= 1) {
        int add = (s >= off) ? tot[s - off] : 0;
        __syncthreads();
        incl += add;
        tot[s] = incl;
        __syncthreads();
    }
    int running = incl - sum;  // exclusive base for this segment
    for (int c = 0; c < nch; c++) {
        chunkoff[c * NSEG + s] = running;
        running += chunkhist[c * NSEG + s];
    }
}

// K5: per-segment f64 sum of gathered scores + argmax -> seg_label.
// argmax(sum) == argmax(mean) since count is a positive per-segment scalar.
__global__ __launch_bounds__(256)
void seg_argmax(const int* __restrict__ sptids, const int* __restrict__ nn_idx,
                const float* __restrict__ scores, int* __restrict__ seg_label, int m) {
    int seg = blockIdx.x, t = threadIdx.x;
    double acc[C];
#pragma unroll
    for (int c = 0; c < C; c++) acc[c] = 0.0;
    for (int i = t; i < m; i += 256) {
        if (sptids[i] == seg) {
            const float* sp = scores + (size_t)nn_idx[i] * C;
#pragma unroll
            for (int c = 0; c < C; c++) acc[c] += (double)sp[c];
        }
    }
#pragma unroll
    for (int c = 0; c < C; c++) {
        for (int off = 32; off > 0; off >>= 1) acc[c] += __shfl_down(acc[c], off, 64);
    }
    __shared__ double wsum[4][C];
    int wid = t >> 6, lane = t & 63;
    if (lane == 0) {
#pragma unroll
        for (int c = 0; c < C; c++) wsum[wid][c] = acc[c];
    }
    __syncthreads();
    if (t == 0) {
        int best = 0;
        double bv = wsum[0][0] + wsum[1][0] + wsum[2][0] + wsum[3][0];
        for (int c = 1; c < C; c++) {
            double v = wsum[0][c] + wsum[1][c] + wsum[2][c] + wsum[3][c];
            if (v > bv) { bv = v; best = c; }  // strict > : first max wins (matches jnp.argmax)
        }
        seg_label[seg] = best;
    }
}

// K6: stable scatter (counting sort) of d_points + labels in original order.
// Output buffer is read back as float32: labels written as float-valued ints at offset m*3.
__global__ __launch_bounds__(256)
void scatter_out(const float* __restrict__ dpts, const int* __restrict__ sptids,
                 const int* __restrict__ chunkoff, const int* __restrict__ seg_label,
                 float* __restrict__ out, int m) {
    __shared__ int segs[256];
    int ch = blockIdx.x, t = threadIdx.x;
    int i = ch * 256 + t;
    int seg = (i < m) ? sptids[i] : -1;
    segs[t] = seg;
    __syncthreads();
    if (i >= m) return;
    int rank = 0;
    for (int j = 0; j < t; j++) rank += (segs[j] == seg) ? 1 : 0;  // stable within chunk
    int pos = chunkoff[ch * NSEG + seg] + rank;
    out[(size_t)pos * 3 + 0] = dpts[(size_t)i * 3 + 0];
    out[(size_t)pos * 3 + 1] = dpts[(size_t)i * 3 + 1];
    out[(size_t)pos * 3 + 2] = dpts[(size_t)i * 3 + 2];
    out[(size_t)m * 3 + i] = (float)seg_label[seg];
}

extern "C" void kernel_launch(void* const* d_in, const int* in_sizes, int n_in,
                              void* d_out, int out_size, void* d_ws, size_t ws_size,
                              hipStream_t stream) {
    const float* points = (const float*)d_in[0];
    const float* scores = (const float*)d_in[1];
    const float* dpts   = (const float*)d_in[2];
    const int*   sptids = (const int*)d_in[3];

    int n = in_sizes[0] / 3;
    int m = in_sizes[2] / 3;
    int PC  = (n + PPB - 1) / PPB;     // 32 point chunks
    int QC  = (m + QPB - 1) / QPB;     // 8 query chunks
    int NCH = (m + 255) / 256;         // 64 chunks for counting sort

    char* ws = (char*)d_ws;
    double* pdist     = (double*)ws;  ws += (size_t)PC * m * sizeof(double);
    int*    pidx      = (int*)ws;     ws += (size_t)PC * m * sizeof(int);
    int*    nn_idx    = (int*)ws;     ws += (size_t)m * sizeof(int);
    int*    chunkhist = (int*)ws;     ws += (size_t)NCH * NSEG * sizeof(int);
    int*    chunkoff  = (int*)ws;     ws += (size_t)NCH * NSEG * sizeof(int);
    int*    seg_label = (int*)ws;     ws += (size_t)NSEG * sizeof(int);

    nn_partial<<<dim3(QC, PC), K1_THREADS, 0, stream>>>(points, dpts, n, m, pdist, pidx);
    nn_reduce<<<(m + 255) / 256, 256, 0, stream>>>(pdist, pidx, nn_idx, m, PC);
    chunk_hist<<<NCH, 256, 0, stream>>>(sptids, chunkhist, m);
    seg_offsets<<<1, NSEG, 0, stream>>>(chunkhist, chunkoff, NCH);
    seg_argmax<<<NSEG, 256, 0, stream>>>(sptids, nn_idx, scores, seg_label, m);
    scatter_out<<<NCH, 256, 0, stream>>>(dpts, sptids, chunkoff, seg_label, (float*)d_out, m);
}